// Round 1
// baseline (69687.085 us; speedup 1.0000x reference)
//
#include <hip/hip_runtime.h>
#include <hip/hip_bf16.h>

// GRU: B=128, T=1024, D_IN=512, H=1024. Output = final hidden state [128,1024] fp32.
//
// Strategy: persistent kernel, 256 WGs x 256 threads (1 per CU). Each WG owns a
// static [16 rows x 32 cols] block of the state for all 3 gates. fp32 state in
// LDS (WG-private); bf16 broadcast copies of h and r*h in global for the
// recurrent GEMMs (MFMA 16x16x32 bf16). Weights pre-transposed to bf16 n-major
// in ws so B-fragments are contiguous 16B loads. 2 custom grid barriers/step.

#define BB   128
#define TT   1024
#define DIN  512
#define HD   1024

typedef short short8 __attribute__((ext_vector_type(8)));
typedef float f32x4 __attribute__((ext_vector_type(4)));

// ws layout (bytes)
#define BAR_OFF  0
#define WT_OFF   1024                      // 3*1024*512 bf16 = 3145728
#define RT_OFF   (WT_OFF + 3*HD*DIN*2)     // 3*1024*1024 bf16 = 6291456
#define HBF_OFF  (RT_OFF + 3*HD*HD*2)      // 128*1024 bf16 = 262144
#define RH_OFF   (HBF_OFF + BB*HD*2)       // 128*1024 bf16 = 262144

__device__ __forceinline__ unsigned short f2bf(float f) {
    unsigned u = __builtin_bit_cast(unsigned, f);
    u = (u + 0x7FFFu + ((u >> 16) & 1u)) >> 16;   // RNE
    return (unsigned short)u;
}

__device__ __forceinline__ short8 ld_bf8(const unsigned short* p) {
    return *(const short8*)p;   // 16B aligned by construction
}

__device__ __forceinline__ short8 cvt_f8(const float* p) {
    const float4* q = (const float4*)p;
    float4 a = q[0], b = q[1];
    short8 r;
    r[0] = (short)f2bf(a.x); r[1] = (short)f2bf(a.y);
    r[2] = (short)f2bf(a.z); r[3] = (short)f2bf(a.w);
    r[4] = (short)f2bf(b.x); r[5] = (short)f2bf(b.y);
    r[6] = (short)f2bf(b.z); r[7] = (short)f2bf(b.w);
    return r;
}

__device__ __forceinline__ void gridbar(unsigned* bar, unsigned target) {
    __syncthreads();
    if (threadIdx.x == 0) {
        __hip_atomic_fetch_add(bar, 1u, __ATOMIC_RELEASE, __HIP_MEMORY_SCOPE_AGENT);
        unsigned v;
        do {
            __builtin_amdgcn_s_sleep(1);
            v = __hip_atomic_load(bar, __ATOMIC_RELAXED, __HIP_MEMORY_SCOPE_AGENT);
        } while (v < target);
    }
    __syncthreads();
    __threadfence();   // acquire: make remote (cross-XCD) writes visible
}

// ---- phase 0: transpose + bf16-convert weights -----------------------------
// z=0..2: W_z,W_r,W_h [512,1024] -> wt[z][n][k]; z=3..5: R_* [1024,1024] -> rt
__global__ void pack_weights(const float* __restrict__ w0, const float* __restrict__ w1,
                             const float* __restrict__ w2, const float* __restrict__ r0,
                             const float* __restrict__ r1, const float* __restrict__ r2,
                             unsigned short* __restrict__ wt, unsigned short* __restrict__ rt) {
    int z = blockIdx.z;
    int K = (z < 3) ? DIN : HD;
    int kb = blockIdx.x * 32;
    if (kb >= K) return;
    int nb = blockIdx.y * 32;
    const float* src = (z == 0) ? w0 : (z == 1) ? w1 : (z == 2) ? w2
                     : (z == 3) ? r0 : (z == 4) ? r1 : r2;
    unsigned short* dst = (z < 3) ? (wt + (size_t)z * HD * DIN)
                                  : (rt + (size_t)(z - 3) * HD * HD);
    __shared__ float tile[32][33];
    int tx = threadIdx.x & 31, ty = threadIdx.x >> 5;
    for (int i = ty; i < 32; i += 8)
        tile[i][tx] = src[(size_t)(kb + i) * HD + nb + tx];
    __syncthreads();
    for (int i = ty; i < 32; i += 8)
        dst[(size_t)(nb + i) * K + kb + tx] = f2bf(tile[tx][i]);
}

// ---- persistent GRU kernel -------------------------------------------------
__launch_bounds__(256, 1)
__global__ void gru_persistent(const float* __restrict__ x,
                               const float* __restrict__ Bz, const float* __restrict__ Br,
                               const float* __restrict__ Bh,
                               const unsigned short* __restrict__ WT,
                               const unsigned short* __restrict__ RT,
                               unsigned short* __restrict__ hbf,
                               unsigned short* __restrict__ rhbf,
                               unsigned* bar, float* __restrict__ out) {
    const int g = blockIdx.x;            // 0..255
    const int rowbase = (g >> 5) * 16;   // batch rows [rowbase, rowbase+16)
    const int colbase = (g & 31) * 32;   // hidden cols [colbase, colbase+32)
    const int wave = threadIdx.x >> 6;   // 0..3
    const int lane = threadIdx.x & 63;
    const int frow = lane & 15;          // A-row / B-col / C-col index
    const int fquad = lane >> 4;         // 0..3 ; A/B k-octet, C row group

    __shared__ float zbuf[16][32];
    __shared__ float hstate[16][32];     // fp32 private state block
    __shared__ float red[2][4][64];      // stage-B K-split partials

    for (int i = threadIdx.x; i < 16 * 32; i += 256)
        (&hstate[0][0])[i] = 0.f;
    __syncthreads();

    unsigned phase = 0;

    for (int t = 0; t < TT; ++t) {
        const float* xrow = x + ((size_t)(rowbase + frow) * TT + t) * DIN;

        // ---------------- stage A: z (waves 0,1), r (waves 2,3) -------------
        {
            const int gate = wave >> 1;                 // 0=z, 1=r
            const int nb = colbase + (wave & 1) * 16;   // tile col base
            f32x4 acc = {0.f, 0.f, 0.f, 0.f};

            const unsigned short* wcol = WT + ((size_t)gate * HD + nb + frow) * DIN;
            for (int kb = 0; kb < DIN; kb += 32) {
                int k0 = kb + fquad * 8;
                short8 a = cvt_f8(xrow + k0);
                short8 b = ld_bf8(wcol + k0);
                acc = __builtin_amdgcn_mfma_f32_16x16x32_bf16(a, b, acc, 0, 0, 0);
            }
            const unsigned short* hrow = hbf + (size_t)(rowbase + frow) * HD;
            const unsigned short* rcol = RT + ((size_t)gate * HD + nb + frow) * HD;
            for (int kb = 0; kb < HD; kb += 32) {
                int k0 = kb + fquad * 8;
                short8 a = ld_bf8(hrow + k0);
                short8 b = ld_bf8(rcol + k0);
                acc = __builtin_amdgcn_mfma_f32_16x16x32_bf16(a, b, acc, 0, 0, 0);
            }
            const int col = nb + frow;                  // absolute hidden col
            const float bv = (gate == 0) ? Bz[col] : Br[col];
            #pragma unroll
            for (int r4 = 0; r4 < 4; ++r4) {
                int row = fquad * 4 + r4;               // within 16
                float pre = acc[r4] + bv;
                float sg = 1.f / (1.f + __expf(-pre));
                if (gate == 0) {
                    zbuf[row][col - colbase] = sg;
                } else {
                    float ho = hstate[row][col - colbase];
                    rhbf[(size_t)(rowbase + row) * HD + col] = f2bf(sg * ho);
                }
            }
        }
        gridbar(bar, ++phase * 256u);

        // ---------------- stage B: h~ (2 tiles, K split across wave pairs) --
        {
            const int tile = wave & 1;                  // which 16-col tile
            const int half = wave >> 1;                 // K-half
            const int nb = colbase + tile * 16;
            f32x4 acc = {0.f, 0.f, 0.f, 0.f};

            const unsigned short* rhrow = rhbf + (size_t)(rowbase + frow) * HD;
            const unsigned short* rcol = RT + ((size_t)2 * HD + nb + frow) * HD;
            if (half == 0) {
                const unsigned short* wcol = WT + ((size_t)2 * HD + nb + frow) * DIN;
                for (int kb = 0; kb < DIN; kb += 32) {          // x @ W_h
                    int k0 = kb + fquad * 8;
                    short8 a = cvt_f8(xrow + k0);
                    short8 b = ld_bf8(wcol + k0);
                    acc = __builtin_amdgcn_mfma_f32_16x16x32_bf16(a, b, acc, 0, 0, 0);
                }
                for (int kb = 0; kb < 256; kb += 32) {          // (r*h) @ R_h lo
                    int k0 = kb + fquad * 8;
                    short8 a = ld_bf8(rhrow + k0);
                    short8 b = ld_bf8(rcol + k0);
                    acc = __builtin_amdgcn_mfma_f32_16x16x32_bf16(a, b, acc, 0, 0, 0);
                }
            } else {
                for (int kb = 256; kb < HD; kb += 32) {         // (r*h) @ R_h hi
                    int k0 = kb + fquad * 8;
                    short8 a = ld_bf8(rhrow + k0);
                    short8 b = ld_bf8(rcol + k0);
                    acc = __builtin_amdgcn_mfma_f32_16x16x32_bf16(a, b, acc, 0, 0, 0);
                }
                #pragma unroll
                for (int r4 = 0; r4 < 4; ++r4) red[tile][r4][lane] = acc[r4];
            }
            __syncthreads();
            if (half == 0) {
                const int col = nb + frow;
                const float bv = Bh[col];
                #pragma unroll
                for (int r4 = 0; r4 < 4; ++r4) {
                    int row = fquad * 4 + r4;
                    float pre = acc[r4] + red[tile][r4][lane] + bv;
                    float ht = tanhf(pre);
                    float zv = zbuf[row][col - colbase];
                    float ho = hstate[row][col - colbase];
                    float hn = (1.f - zv) * ho + zv * ht;
                    hstate[row][col - colbase] = hn;
                    hbf[(size_t)(rowbase + row) * HD + col] = f2bf(hn);
                    if (t == TT - 1)
                        out[(size_t)(rowbase + row) * HD + col] = hn;
                }
            }
        }
        gridbar(bar, ++phase * 256u);
    }
}

extern "C" void kernel_launch(void* const* d_in, const int* in_sizes, int n_in,
                              void* d_out, int out_size, void* d_ws, size_t ws_size,
                              hipStream_t stream) {
    const float* x  = (const float*)d_in[0];
    const float* Wz = (const float*)d_in[1];
    const float* Wr = (const float*)d_in[2];
    const float* Wh = (const float*)d_in[3];
    const float* Rz = (const float*)d_in[4];
    const float* Rr = (const float*)d_in[5];
    const float* Rh = (const float*)d_in[6];
    const float* Bz = (const float*)d_in[7];
    const float* Br = (const float*)d_in[8];
    const float* Bh = (const float*)d_in[9];

    char* ws = (char*)d_ws;
    unsigned*       bar  = (unsigned*)(ws + BAR_OFF);
    unsigned short* WT   = (unsigned short*)(ws + WT_OFF);
    unsigned short* RT   = (unsigned short*)(ws + RT_OFF);
    unsigned short* hbf  = (unsigned short*)(ws + HBF_OFF);
    unsigned short* rhbf = (unsigned short*)(ws + RH_OFF);

    // barrier counter = 0; h broadcast = +0.0 bf16
    hipMemsetAsync(ws + BAR_OFF, 0, 1024, stream);
    hipMemsetAsync(ws + HBF_OFF, 0, BB * HD * 2, stream);

    dim3 pgrid(HD / 32, HD / 32, 6);
    pack_weights<<<pgrid, 256, 0, stream>>>(Wz, Wr, Wh, Rz, Rr, Rh, WT, RT);

    gru_persistent<<<256, 256, 0, stream>>>(x, Bz, Br, Bh, WT, RT, hbf, rhbf,
                                            bar, (float*)d_out);
}

// Round 2
// 21839.610 us; speedup vs baseline: 3.1909x; 3.1909x over previous
//
#include <hip/hip_runtime.h>
#include <hip/hip_bf16.h>

// GRU: B=128, T=1024, D_IN=512, H=1024. Output = final hidden state [128,1024] fp32.
//
// Round 2: fence-free cross-XCD coherence. All mutable cross-WG data (h, r*h,
// barrier flags) moves via relaxed AGENT-scope 8B atomics (sc0 sc1: bypass
// L1/L2, coherent at L3). No buffer_wbl2/buffer_inv -> constant weights stay
// L2-resident across all 1024 steps. Barrier = all-to-all flag array (no RMW).
// h / r*h / x staged once per stage into LDS (padded strides, stride % 32
// dwords == 4 -> conflict-free-ish b128 reads).

#define BB   128
#define TT   1024
#define DIN  512
#define HD   1024

typedef short short8 __attribute__((ext_vector_type(8)));
typedef float f32x4 __attribute__((ext_vector_type(4)));
typedef unsigned long long ull;

// ws layout (bytes)
#define FLAGS_OFF 0                        // 256 flags, 64B stride = 16384
#define WT_OFF    16384                    // 3*1024*512  bf16 = 3145728
#define RT_OFF    (WT_OFF + 3*HD*DIN*2)    // 3*1024*1024 bf16 = 6291456
#define HBF_OFF   (RT_OFF + 3*HD*HD*2)     // 128*1024 bf16 = 262144
#define RH_OFF    (HBF_OFF + BB*HD*2)      // 128*1024 bf16 = 262144

#define FLAG_STRIDE 16                     // uints (64B)

__device__ __forceinline__ unsigned short f2bf(float f) {
    unsigned u = __builtin_bit_cast(unsigned, f);
    u = (u + 0x7FFFu + ((u >> 16) & 1u)) >> 16;   // RNE
    return (unsigned short)u;
}

__device__ __forceinline__ ull pack4(const float* p) {
    return (ull)f2bf(p[0]) | ((ull)f2bf(p[1]) << 16) |
           ((ull)f2bf(p[2]) << 32) | ((ull)f2bf(p[3]) << 48);
}

__device__ __forceinline__ short8 ld8(const unsigned short* p) {
    return *(const short8*)p;
}

// All-to-all barrier: WG i publishes flags[i*16] = phase (relaxed agent store,
// ordered after data stores by the vmcnt(0) drain before s_barrier); thread j
// polls flags[j*16]. No RMW, no cache-wide fences.
__device__ __forceinline__ void gridbar(unsigned* flags, unsigned phase) {
    __syncthreads();                       // drains each wave's vmem stores
    if (threadIdx.x == 0)
        __hip_atomic_store(flags + (unsigned)blockIdx.x * FLAG_STRIDE, phase,
                           __ATOMIC_RELAXED, __HIP_MEMORY_SCOPE_AGENT);
    unsigned* my = flags + threadIdx.x * FLAG_STRIDE;
    while (__hip_atomic_load(my, __ATOMIC_RELAXED, __HIP_MEMORY_SCOPE_AGENT) < phase)
        __builtin_amdgcn_s_sleep(1);
    __syncthreads();
}

// ---- phase 0: transpose + bf16-convert weights -----------------------------
__global__ void pack_weights(const float* __restrict__ w0, const float* __restrict__ w1,
                             const float* __restrict__ w2, const float* __restrict__ r0,
                             const float* __restrict__ r1, const float* __restrict__ r2,
                             unsigned short* __restrict__ wt, unsigned short* __restrict__ rt) {
    int z = blockIdx.z;
    int K = (z < 3) ? DIN : HD;
    int kb = blockIdx.x * 32;
    if (kb >= K) return;
    int nb = blockIdx.y * 32;
    const float* src = (z == 0) ? w0 : (z == 1) ? w1 : (z == 2) ? w2
                     : (z == 3) ? r0 : (z == 4) ? r1 : r2;
    unsigned short* dst = (z < 3) ? (wt + (size_t)z * HD * DIN)
                                  : (rt + (size_t)(z - 3) * HD * HD);
    __shared__ float tile[32][33];
    int tx = threadIdx.x & 31, ty = threadIdx.x >> 5;
    for (int i = ty; i < 32; i += 8)
        tile[i][tx] = src[(size_t)(kb + i) * HD + nb + tx];
    __syncthreads();
    for (int i = ty; i < 32; i += 8)
        dst[(size_t)(nb + i) * K + kb + tx] = f2bf(tile[tx][i]);
}

// ---- persistent GRU kernel -------------------------------------------------
__launch_bounds__(256, 1)
__global__ void gru_persistent(const float* __restrict__ x,
                               const float* __restrict__ Bz, const float* __restrict__ Br,
                               const float* __restrict__ Bh,
                               const unsigned short* __restrict__ WT,
                               const unsigned short* __restrict__ RT,
                               unsigned short* __restrict__ hbf,
                               unsigned short* __restrict__ rhbf,
                               unsigned* __restrict__ flags,
                               float* __restrict__ out) {
    const int g = blockIdx.x;            // 0..255
    const int rowbase = (g >> 5) * 16;   // batch rows
    const int colbase = (g & 31) * 32;   // hidden cols
    const int tid  = threadIdx.x;
    const int wave = tid >> 6;
    const int lane = tid & 63;
    const int frow = lane & 15;
    const int fquad = lane >> 4;
    const int k0 = fquad * 8;

    // padded strides: bytes%16==0 for b128 align; dwords%32==4 for banks
    __shared__ unsigned short xsh[16][520];    // x[t] bf16, 16 rows x 512
    __shared__ unsigned short hsh[16][1032];   // h bf16, 16 rows x 1024
    __shared__ unsigned short rhsh[16][1032];  // r*h bf16
    __shared__ float zbuf[16][36];
    __shared__ float rtmp[16][36];
    __shared__ float hstate[16][36];           // fp32 private state block
    __shared__ float red[2][4][64];

    if (tid < 128) {
        int row = tid >> 3, c4 = tid & 7;
        *(float4*)&hstate[row][c4 * 4] = make_float4(0.f, 0.f, 0.f, 0.f);
    }

    // t-invariant weight column pointers + biases (hoisted out of the loop)
    const int gateA = wave >> 1;               // 0=z, 1=r
    const int nbA = colbase + (wave & 1) * 16;
    const unsigned short* wcolA = WT + ((size_t)gateA * HD + nbA + frow) * DIN;
    const unsigned short* rcolA = RT + ((size_t)gateA * HD + nbA + frow) * HD;
    const float bvA = (gateA == 0) ? Bz[nbA + frow] : Br[nbA + frow];

    const int tileB = wave & 1;
    const int halfB = wave >> 1;
    const int nbB = colbase + tileB * 16;
    const unsigned short* wcolB = WT + ((size_t)2 * HD + nbB + frow) * DIN;
    const unsigned short* rcolB = RT + ((size_t)2 * HD + nbB + frow) * HD;
    const float bvB = Bh[nbB + frow];

    const ull* hbf_u = (const ull*)hbf;
    const ull* rh_u  = (const ull*)rhbf;
    unsigned phase = 0;

    for (int t = 0; t < TT; ++t) {
        // ---- stage x[t] (cached loads, constant data) + h (coherent loads) --
        #pragma unroll
        for (int i = tid; i < 2048; i += 256) {        // 8 iters/thread
            int row = i >> 7, c4 = i & 127;
            float4 v = ((const float4*)(x + ((size_t)(rowbase + row) * TT + t) * DIN))[c4];
            ull pk = (ull)f2bf(v.x) | ((ull)f2bf(v.y) << 16) |
                     ((ull)f2bf(v.z) << 32) | ((ull)f2bf(v.w) << 48);
            *(ull*)&xsh[row][c4 * 4] = pk;
        }
        #pragma unroll
        for (int i = tid; i < 4096; i += 256) {        // 16 iters/thread
            int row = i >> 8, c8 = i & 255;
            ull v = __hip_atomic_load(hbf_u + (size_t)(rowbase + row) * 256 + c8,
                                      __ATOMIC_RELAXED, __HIP_MEMORY_SCOPE_AGENT);
            *(ull*)&hsh[row][c8 * 4] = v;
        }
        __syncthreads();

        // ---- stage A: z (waves 0,1), r (waves 2,3); 2 acc chains ----------
        {
            f32x4 a0 = {0.f, 0.f, 0.f, 0.f}, a1 = {0.f, 0.f, 0.f, 0.f};
            for (int kb = 0; kb < DIN; kb += 64) {
                a0 = __builtin_amdgcn_mfma_f32_16x16x32_bf16(
                        ld8(&xsh[frow][kb + k0]), ld8(wcolA + kb + k0), a0, 0, 0, 0);
                a1 = __builtin_amdgcn_mfma_f32_16x16x32_bf16(
                        ld8(&xsh[frow][kb + k0 + 32]), ld8(wcolA + kb + k0 + 32), a1, 0, 0, 0);
            }
            for (int kb = 0; kb < HD; kb += 64) {
                a0 = __builtin_amdgcn_mfma_f32_16x16x32_bf16(
                        ld8(&hsh[frow][kb + k0]), ld8(rcolA + kb + k0), a0, 0, 0, 0);
                a1 = __builtin_amdgcn_mfma_f32_16x16x32_bf16(
                        ld8(&hsh[frow][kb + k0 + 32]), ld8(rcolA + kb + k0 + 32), a1, 0, 0, 0);
            }
            const int c = nbA + frow - colbase;
            #pragma unroll
            for (int r4 = 0; r4 < 4; ++r4) {
                int row = fquad * 4 + r4;
                float pre = a0[r4] + a1[r4] + bvA;
                float sg = 1.f / (1.f + __expf(-pre));
                if (gateA == 0) zbuf[row][c] = sg;
                else            rtmp[row][c] = sg * hstate[row][c];
            }
        }
        __syncthreads();
        if (tid < 128) {                               // publish r*h (bf16, coherent)
            int row = tid >> 3, c4 = tid & 7;
            __hip_atomic_store((ull*)rhbf + (size_t)(rowbase + row) * 256 + (colbase >> 2) + c4,
                               pack4(&rtmp[row][c4 * 4]),
                               __ATOMIC_RELAXED, __HIP_MEMORY_SCOPE_AGENT);
        }
        gridbar(flags, ++phase);

        // ---- stage r*h into LDS -------------------------------------------
        #pragma unroll
        for (int i = tid; i < 4096; i += 256) {
            int row = i >> 8, c8 = i & 255;
            ull v = __hip_atomic_load(rh_u + (size_t)(rowbase + row) * 256 + c8,
                                      __ATOMIC_RELAXED, __HIP_MEMORY_SCOPE_AGENT);
            *(ull*)&rhsh[row][c8 * 4] = v;
        }
        __syncthreads();

        // ---- stage B: h~ (2 col tiles x 2 K-halves) -----------------------
        {
            f32x4 a0 = {0.f, 0.f, 0.f, 0.f}, a1 = {0.f, 0.f, 0.f, 0.f};
            if (halfB == 0) {
                for (int kb = 0; kb < DIN; kb += 64) {
                    a0 = __builtin_amdgcn_mfma_f32_16x16x32_bf16(
                            ld8(&xsh[frow][kb + k0]), ld8(wcolB + kb + k0), a0, 0, 0, 0);
                    a1 = __builtin_amdgcn_mfma_f32_16x16x32_bf16(
                            ld8(&xsh[frow][kb + k0 + 32]), ld8(wcolB + kb + k0 + 32), a1, 0, 0, 0);
                }
                for (int kb = 0; kb < 256; kb += 64) {
                    a0 = __builtin_amdgcn_mfma_f32_16x16x32_bf16(
                            ld8(&rhsh[frow][kb + k0]), ld8(rcolB + kb + k0), a0, 0, 0, 0);
                    a1 = __builtin_amdgcn_mfma_f32_16x16x32_bf16(
                            ld8(&rhsh[frow][kb + k0 + 32]), ld8(rcolB + kb + k0 + 32), a1, 0, 0, 0);
                }
            } else {
                for (int kb = 256; kb < HD; kb += 64) {
                    a0 = __builtin_amdgcn_mfma_f32_16x16x32_bf16(
                            ld8(&rhsh[frow][kb + k0]), ld8(rcolB + kb + k0), a0, 0, 0, 0);
                    a1 = __builtin_amdgcn_mfma_f32_16x16x32_bf16(
                            ld8(&rhsh[frow][kb + k0 + 32]), ld8(rcolB + kb + k0 + 32), a1, 0, 0, 0);
                }
                #pragma unroll
                for (int r4 = 0; r4 < 4; ++r4) red[tileB][r4][lane] = a0[r4] + a1[r4];
            }
            __syncthreads();
            if (halfB == 0) {
                const int c = nbB + frow - colbase;
                #pragma unroll
                for (int r4 = 0; r4 < 4; ++r4) {
                    int row = fquad * 4 + r4;
                    float pre = a0[r4] + a1[r4] + red[tileB][r4][lane] + bvB;
                    float ht = tanhf(pre);
                    float zv = zbuf[row][c];
                    float ho = hstate[row][c];
                    hstate[row][c] = (1.f - zv) * ho + zv * ht;
                }
            }
        }
        __syncthreads();
        if (tid < 128) {                               // publish h (bf16, coherent)
            int row = tid >> 3, c4 = tid & 7;
            __hip_atomic_store((ull*)hbf + (size_t)(rowbase + row) * 256 + (colbase >> 2) + c4,
                               pack4(&hstate[row][c4 * 4]),
                               __ATOMIC_RELAXED, __HIP_MEMORY_SCOPE_AGENT);
        }
        gridbar(flags, ++phase);
    }

    if (tid < 128) {                                   // final output, fp32
        int row = tid >> 3, c4 = tid & 7;
        *(float4*)(out + (size_t)(rowbase + row) * HD + colbase + c4 * 4) =
            *(float4*)&hstate[row][c4 * 4];
    }
}

extern "C" void kernel_launch(void* const* d_in, const int* in_sizes, int n_in,
                              void* d_out, int out_size, void* d_ws, size_t ws_size,
                              hipStream_t stream) {
    const float* x  = (const float*)d_in[0];
    const float* Wz = (const float*)d_in[1];
    const float* Wr = (const float*)d_in[2];
    const float* Wh = (const float*)d_in[3];
    const float* Rz = (const float*)d_in[4];
    const float* Rr = (const float*)d_in[5];
    const float* Rh = (const float*)d_in[6];
    const float* Bz = (const float*)d_in[7];
    const float* Br = (const float*)d_in[8];
    const float* Bh = (const float*)d_in[9];

    char* ws = (char*)d_ws;
    unsigned*       flags = (unsigned*)(ws + FLAGS_OFF);
    unsigned short* WT    = (unsigned short*)(ws + WT_OFF);
    unsigned short* RT    = (unsigned short*)(ws + RT_OFF);
    unsigned short* hbf   = (unsigned short*)(ws + HBF_OFF);
    unsigned short* rhbf  = (unsigned short*)(ws + RH_OFF);

    hipMemsetAsync(ws + FLAGS_OFF, 0, 16384, stream);        // flags = 0
    hipMemsetAsync(ws + HBF_OFF, 0, BB * HD * 2, stream);    // h0 = 0

    dim3 pgrid(HD / 32, HD / 32, 6);
    pack_weights<<<pgrid, 256, 0, stream>>>(Wz, Wr, Wh, Rz, Rr, Rh, WT, RT);

    gru_persistent<<<256, 256, 0, stream>>>(x, Bz, Br, Bh, WT, RT, hbf, rhbf,
                                            flags, (float*)d_out);
}

// Round 3
// 12749.228 us; speedup vs baseline: 5.4660x; 1.7130x over previous
//
#include <hip/hip_runtime.h>
#include <hip/hip_bf16.h>

// GRU: B=128, T=1024, D_IN=512, H=1024. Output = final hidden state [128,1024] fp32.
//
// Round 3: weights live in REGISTERS. 256 WGs x 512 threads (8 waves/CU).
// Each CU owns a [16 rows x 32 cols] state block; its full weight working set
// (W_z,W_r,W_h cols x 512K + R_z,R_r,R_h cols x 1024K = 288 KB bf16) is
// preloaded once into per-wave VGPR B-fragments -> no weight traffic in the
// 1024-step loop. Cross-WG h / r*h via relaxed agent-scope 8B atomics (L3
// coherent, no fences). All-to-all flag barrier. x[t+1] staged during the
// phase-B barrier wait (barrier-independent prefetch).

#define BB   128
#define TT   1024
#define DIN  512
#define HD   1024

typedef short short8 __attribute__((ext_vector_type(8)));
typedef float f32x4 __attribute__((ext_vector_type(4)));
typedef unsigned long long ull;

// ws layout (bytes)
#define FLAGS_OFF 0                        // 256 flags, 64B stride = 16384
#define WT_OFF    16384                    // 3*1024*512  bf16
#define RT_OFF    (WT_OFF + 3*HD*DIN*2)    // 3*1024*1024 bf16
#define HBF_OFF   (RT_OFF + 3*HD*HD*2)     // 128*1024 bf16
#define RH_OFF    (HBF_OFF + BB*HD*2)      // 128*1024 bf16

#define FLAG_STRIDE 16                     // uints (64B)

__device__ __forceinline__ unsigned short f2bf(float f) {
    unsigned u = __builtin_bit_cast(unsigned, f);
    u = (u + 0x7FFFu + ((u >> 16) & 1u)) >> 16;   // RNE
    return (unsigned short)u;
}

__device__ __forceinline__ ull pack4(const float* p) {
    return (ull)f2bf(p[0]) | ((ull)f2bf(p[1]) << 16) |
           ((ull)f2bf(p[2]) << 32) | ((ull)f2bf(p[3]) << 48);
}

__device__ __forceinline__ ull pack4v(float4 v) {
    return (ull)f2bf(v.x) | ((ull)f2bf(v.y) << 16) |
           ((ull)f2bf(v.z) << 32) | ((ull)f2bf(v.w) << 48);
}

__device__ __forceinline__ short8 ld8(const unsigned short* p) {
    return *(const short8*)p;
}

#define MFMA(A, B, C) __builtin_amdgcn_mfma_f32_16x16x32_bf16((A), (B), (C), 0, 0, 0)

// All-to-all barrier: WG i publishes flags[i*16]=phase; threads 0..255 poll one
// flag each. No RMW, no cache-wide fences (mutable data is agent-scope sc0sc1).
__device__ __forceinline__ void gridbar(unsigned* flags, unsigned phase) {
    __syncthreads();
    if (threadIdx.x == 0)
        __hip_atomic_store(flags + (unsigned)blockIdx.x * FLAG_STRIDE, phase,
                           __ATOMIC_RELAXED, __HIP_MEMORY_SCOPE_AGENT);
    if (threadIdx.x < 256) {
        unsigned* my = flags + threadIdx.x * FLAG_STRIDE;
        while (__hip_atomic_load(my, __ATOMIC_RELAXED, __HIP_MEMORY_SCOPE_AGENT) < phase)
            __builtin_amdgcn_s_sleep(1);
    }
    __syncthreads();
}

// ---- phase 0: transpose + bf16-convert weights -----------------------------
__global__ void pack_weights(const float* __restrict__ w0, const float* __restrict__ w1,
                             const float* __restrict__ w2, const float* __restrict__ r0,
                             const float* __restrict__ r1, const float* __restrict__ r2,
                             unsigned short* __restrict__ wt, unsigned short* __restrict__ rt) {
    int z = blockIdx.z;
    int K = (z < 3) ? DIN : HD;
    int kb = blockIdx.x * 32;
    if (kb >= K) return;
    int nb = blockIdx.y * 32;
    const float* src = (z == 0) ? w0 : (z == 1) ? w1 : (z == 2) ? w2
                     : (z == 3) ? r0 : (z == 4) ? r1 : r2;
    unsigned short* dst = (z < 3) ? (wt + (size_t)z * HD * DIN)
                                  : (rt + (size_t)(z - 3) * HD * HD);
    __shared__ float tile[32][33];
    int tx = threadIdx.x & 31, ty = threadIdx.x >> 5;
    for (int i = ty; i < 32; i += 8)
        tile[i][tx] = src[(size_t)(kb + i) * HD + nb + tx];
    __syncthreads();
    for (int i = ty; i < 32; i += 8)
        dst[(size_t)(nb + i) * K + kb + tx] = f2bf(tile[tx][i]);
}

// ---- persistent GRU kernel -------------------------------------------------
__launch_bounds__(512, 2)
__global__ void gru_persistent(const float* __restrict__ x,
                               const float* __restrict__ Bz, const float* __restrict__ Br,
                               const float* __restrict__ Bh,
                               const unsigned short* __restrict__ WT,
                               const unsigned short* __restrict__ RT,
                               unsigned short* __restrict__ hbf,
                               unsigned short* __restrict__ rhbf,
                               unsigned* __restrict__ flags,
                               float* __restrict__ out) {
    const int g = blockIdx.x;            // 0..255
    const int rowbase = (g >> 5) * 16;   // batch rows
    const int colbase = (g & 31) * 32;   // hidden cols
    const int tid  = threadIdx.x;
    const int w    = tid >> 6;           // 0..7
    const int lane = tid & 63;
    const int frow = lane & 15;
    const int fquad = lane >> 4;
    const int k0 = fquad * 8;

    // stage A role: gate gA (0=z,1=r), col tile cA, K-half hA
    const int gA = (w >> 2) & 1;
    const int cA = (w >> 1) & 1;
    const int hA = w & 1;
    // stage B role: col tile cB, K-quarter role rB
    const int cB = w & 1;
    const int rB = w >> 1;               // 0,1: x-halves; 2,3: rh-halves

    // padded strides: bytes%16==0 for b128 align; dwords%32==4 for banks
    __shared__ unsigned short xsh[16][520];
    __shared__ unsigned short hsh[16][1032];
    __shared__ unsigned short rhsh[16][1032];
    __shared__ float zbuf[16][36];
    __shared__ float rtmp[16][36];
    __shared__ float hstate[16][36];
    __shared__ float redA[2][2][4][64];
    __shared__ float redB[2][3][4][64];

    if (tid < 128) {
        int row = tid >> 3, c4 = tid & 7;
        *(float4*)&hstate[row][c4 * 4] = make_float4(0.f, 0.f, 0.f, 0.f);
    }

    // ---- preload ALL weights into registers (per-wave B-fragments) --------
    short8 wAr[24];
    short8 wBr[16];
    {
        const unsigned short* wcolA = WT + ((size_t)gA * HD + colbase + cA * 16 + frow) * DIN;
        const unsigned short* rcolA = RT + ((size_t)gA * HD + colbase + cA * 16 + frow) * HD;
        if (hA == 0) {
            #pragma unroll
            for (int i = 0; i < 16; ++i) wAr[i] = ld8(wcolA + i * 32 + k0);
            #pragma unroll
            for (int i = 0; i < 8; ++i)  wAr[16 + i] = ld8(rcolA + i * 32 + k0);
        } else {
            #pragma unroll
            for (int i = 0; i < 24; ++i) wAr[i] = ld8(rcolA + (8 + i) * 32 + k0);
        }
        const unsigned short* wcolB = WT + ((size_t)2 * HD + colbase + cB * 16 + frow) * DIN;
        const unsigned short* rcolB = RT + ((size_t)2 * HD + colbase + cB * 16 + frow) * HD;
        if (rB == 0) {
            #pragma unroll
            for (int i = 0; i < 8; ++i)  wBr[i] = ld8(wcolB + i * 32 + k0);
        } else if (rB == 1) {
            #pragma unroll
            for (int i = 0; i < 8; ++i)  wBr[i] = ld8(wcolB + (8 + i) * 32 + k0);
        } else if (rB == 2) {
            #pragma unroll
            for (int i = 0; i < 16; ++i) wBr[i] = ld8(rcolB + i * 32 + k0);
        } else {
            #pragma unroll
            for (int i = 0; i < 16; ++i) wBr[i] = ld8(rcolB + (16 + i) * 32 + k0);
        }
    }
    const float bvA = (gA == 0 ? Bz : Br)[colbase + cA * 16 + frow];
    const float bvB = Bh[colbase + cB * 16 + frow];

    const ull* hbf_u = (const ull*)hbf;
    const ull* rh_u  = (const ull*)rhbf;

    // stage x[0]
    #pragma unroll
    for (int i = tid; i < 2048; i += 512) {
        int row = i >> 7, c4 = i & 127;
        float4 v = ((const float4*)(x + (size_t)(rowbase + row) * TT * DIN))[c4];
        *(ull*)&xsh[row][c4 * 4] = pack4v(v);
    }

    unsigned phase = 0;

    for (int t = 0; t < TT; ++t) {
        // ---- stage h (coherent L3 loads) ----------------------------------
        #pragma unroll
        for (int i = tid; i < 4096; i += 512) {        // 8 iters/thread
            int row = i >> 8, c8 = i & 255;
            ull v = __hip_atomic_load(hbf_u + (size_t)(rowbase + row) * 256 + c8,
                                      __ATOMIC_RELAXED, __HIP_MEMORY_SCOPE_AGENT);
            *(ull*)&hsh[row][c8 * 4] = v;
        }
        __syncthreads();

        // ---- stage A: z, r (weights from registers) -----------------------
        {
            f32x4 a0 = {0.f, 0.f, 0.f, 0.f}, a1 = {0.f, 0.f, 0.f, 0.f};
            if (hA == 0) {
                #pragma unroll
                for (int i = 0; i < 16; i += 2) {
                    a0 = MFMA(ld8(&xsh[frow][i * 32 + k0]), wAr[i], a0);
                    a1 = MFMA(ld8(&xsh[frow][(i + 1) * 32 + k0]), wAr[i + 1], a1);
                }
                #pragma unroll
                for (int i = 0; i < 8; i += 2) {
                    a0 = MFMA(ld8(&hsh[frow][i * 32 + k0]), wAr[16 + i], a0);
                    a1 = MFMA(ld8(&hsh[frow][(i + 1) * 32 + k0]), wAr[17 + i], a1);
                }
            } else {
                #pragma unroll
                for (int i = 0; i < 24; i += 2) {
                    a0 = MFMA(ld8(&hsh[frow][(8 + i) * 32 + k0]), wAr[i], a0);
                    a1 = MFMA(ld8(&hsh[frow][(9 + i) * 32 + k0]), wAr[i + 1], a1);
                }
                #pragma unroll
                for (int r4 = 0; r4 < 4; ++r4)
                    redA[gA][cA][r4][lane] = a0[r4] + a1[r4];
            }
            __syncthreads();
            if (hA == 0) {
                const int c = cA * 16 + frow;
                #pragma unroll
                for (int r4 = 0; r4 < 4; ++r4) {
                    int row = fquad * 4 + r4;
                    float pre = a0[r4] + a1[r4] + redA[gA][cA][r4][lane] + bvA;
                    float sg = 1.f / (1.f + __expf(-pre));
                    if (gA == 0) zbuf[row][c] = sg;
                    else         rtmp[row][c] = sg * hstate[row][c];
                }
            }
        }
        __syncthreads();
        if (tid < 128) {                               // publish r*h
            int row = tid >> 3, c4 = tid & 7;
            __hip_atomic_store((ull*)rhbf + (size_t)(rowbase + row) * 256 + (colbase >> 2) + c4,
                               pack4(&rtmp[row][c4 * 4]),
                               __ATOMIC_RELAXED, __HIP_MEMORY_SCOPE_AGENT);
        }
        gridbar(flags, ++phase);

        // ---- stage r*h ----------------------------------------------------
        #pragma unroll
        for (int i = tid; i < 4096; i += 512) {
            int row = i >> 8, c8 = i & 255;
            ull v = __hip_atomic_load(rh_u + (size_t)(rowbase + row) * 256 + c8,
                                      __ATOMIC_RELAXED, __HIP_MEMORY_SCOPE_AGENT);
            *(ull*)&rhsh[row][c8 * 4] = v;
        }
        __syncthreads();

        // ---- stage B: h~ --------------------------------------------------
        {
            f32x4 b0 = {0.f, 0.f, 0.f, 0.f}, b1 = {0.f, 0.f, 0.f, 0.f};
            if (rB == 0) {
                #pragma unroll
                for (int i = 0; i < 8; i += 2) {
                    b0 = MFMA(ld8(&xsh[frow][i * 32 + k0]), wBr[i], b0);
                    b1 = MFMA(ld8(&xsh[frow][(i + 1) * 32 + k0]), wBr[i + 1], b1);
                }
            } else if (rB == 1) {
                #pragma unroll
                for (int i = 0; i < 8; i += 2) {
                    b0 = MFMA(ld8(&xsh[frow][(8 + i) * 32 + k0]), wBr[i], b0);
                    b1 = MFMA(ld8(&xsh[frow][(9 + i) * 32 + k0]), wBr[i + 1], b1);
                }
            } else if (rB == 2) {
                #pragma unroll
                for (int i = 0; i < 16; i += 2) {
                    b0 = MFMA(ld8(&rhsh[frow][i * 32 + k0]), wBr[i], b0);
                    b1 = MFMA(ld8(&rhsh[frow][(i + 1) * 32 + k0]), wBr[i + 1], b1);
                }
            } else {
                #pragma unroll
                for (int i = 0; i < 16; i += 2) {
                    b0 = MFMA(ld8(&rhsh[frow][(16 + i) * 32 + k0]), wBr[i], b0);
                    b1 = MFMA(ld8(&rhsh[frow][(17 + i) * 32 + k0]), wBr[i + 1], b1);
                }
            }
            if (rB > 0) {
                #pragma unroll
                for (int r4 = 0; r4 < 4; ++r4)
                    redB[cB][rB - 1][r4][lane] = b0[r4] + b1[r4];
            }
            __syncthreads();
            if (rB == 0) {
                const int c = cB * 16 + frow;
                #pragma unroll
                for (int r4 = 0; r4 < 4; ++r4) {
                    int row = fquad * 4 + r4;
                    float pre = b0[r4] + b1[r4] + redB[cB][0][r4][lane]
                              + redB[cB][1][r4][lane] + redB[cB][2][r4][lane] + bvB;
                    float ht = tanhf(pre);
                    float zv = zbuf[row][c];
                    float ho = hstate[row][c];
                    hstate[row][c] = ho + zv * (ht - ho);
                }
            }
        }
        __syncthreads();

        if (t + 1 < TT) {
            // prefetch x[t+1] — overlaps the publish + barrier below
            #pragma unroll
            for (int i = tid; i < 2048; i += 512) {
                int row = i >> 7, c4 = i & 127;
                float4 v = ((const float4*)(x + ((size_t)(rowbase + row) * TT + t + 1) * DIN))[c4];
                *(ull*)&xsh[row][c4 * 4] = pack4v(v);
            }
            if (tid < 128) {                           // publish h
                int row = tid >> 3, c4 = tid & 7;
                __hip_atomic_store((ull*)hbf + (size_t)(rowbase + row) * 256 + (colbase >> 2) + c4,
                                   pack4(&hstate[row][c4 * 4]),
                                   __ATOMIC_RELAXED, __HIP_MEMORY_SCOPE_AGENT);
            }
            gridbar(flags, ++phase);
        }
    }

    if (tid < 128) {                                   // final output, fp32
        int row = tid >> 3, c4 = tid & 7;
        *(float4*)(out + (size_t)(rowbase + row) * HD + colbase + c4 * 4) =
            *(float4*)&hstate[row][c4 * 4];
    }
}

extern "C" void kernel_launch(void* const* d_in, const int* in_sizes, int n_in,
                              void* d_out, int out_size, void* d_ws, size_t ws_size,
                              hipStream_t stream) {
    const float* x  = (const float*)d_in[0];
    const float* Wz = (const float*)d_in[1];
    const float* Wr = (const float*)d_in[2];
    const float* Wh = (const float*)d_in[3];
    const float* Rz = (const float*)d_in[4];
    const float* Rr = (const float*)d_in[5];
    const float* Rh = (const float*)d_in[6];
    const float* Bz = (const float*)d_in[7];
    const float* Br = (const float*)d_in[8];
    const float* Bh = (const float*)d_in[9];

    char* ws = (char*)d_ws;
    unsigned*       flags = (unsigned*)(ws + FLAGS_OFF);
    unsigned short* WT    = (unsigned short*)(ws + WT_OFF);
    unsigned short* RT    = (unsigned short*)(ws + RT_OFF);
    unsigned short* hbf   = (unsigned short*)(ws + HBF_OFF);
    unsigned short* rhbf  = (unsigned short*)(ws + RH_OFF);

    hipMemsetAsync(ws + FLAGS_OFF, 0, 16384, stream);        // flags = 0
    hipMemsetAsync(ws + HBF_OFF, 0, BB * HD * 2, stream);    // h0 = 0

    dim3 pgrid(HD / 32, HD / 32, 6);
    pack_weights<<<pgrid, 256, 0, stream>>>(Wz, Wr, Wh, Rz, Rr, Rh, WT, RT);

    gru_persistent<<<256, 512, 0, stream>>>(x, Bz, Br, Bh, WT, RT, hbf, rhbf,
                                            flags, (float*)d_out);
}

// Round 4
// 10056.920 us; speedup vs baseline: 6.9293x; 1.2677x over previous
//
#include <hip/hip_runtime.h>
#include <hip/hip_bf16.h>

// GRU: B=128, T=1024, D_IN=512, H=1024. Output = final hidden state [128,1024] fp32.
//
// Round 4: group-local barriers. The r*h / h exchanges only couple the 32 WGs
// sharing a 16-row batch group -> sync domain shrinks 256 -> 32, with flags
// PACKED into 2 cache lines per group (poll = 2 L3 line reads, was 256 lines).
// Groups are fully decoupled (disjoint buffers+flags); group = blockIdx%8 for
// XCD affinity. x@W_h moved into phase 1 (hidden under h-load latency); phase-2
// rh A-fragments load directly from L3 (skip LDS round-trip); x[t+1] prefetch
// overlaps the barrier-1 poll. Weights stay register/AGPR-resident.

#define BB   128
#define TT   1024
#define DIN  512
#define HD   1024

typedef short short8 __attribute__((ext_vector_type(8)));
typedef float f32x4 __attribute__((ext_vector_type(4)));
typedef unsigned long long ull;

// ws layout (bytes)
#define FLAGS_OFF 0                        // 8 groups * 32 flags * 4B = 1024
#define WT_OFF    16384
#define RT_OFF    (WT_OFF + 3*HD*DIN*2)
#define HBF_OFF   (RT_OFF + 3*HD*HD*2)
#define RH_OFF    (HBF_OFF + BB*HD*2)

__device__ __forceinline__ unsigned short f2bf(float f) {
    unsigned u = __builtin_bit_cast(unsigned, f);
    u = (u + 0x7FFFu + ((u >> 16) & 1u)) >> 16;   // RNE
    return (unsigned short)u;
}

__device__ __forceinline__ ull pack4(const float* p) {
    return (ull)f2bf(p[0]) | ((ull)f2bf(p[1]) << 16) |
           ((ull)f2bf(p[2]) << 32) | ((ull)f2bf(p[3]) << 48);
}

__device__ __forceinline__ ull pack4v(float4 v) {
    return (ull)f2bf(v.x) | ((ull)f2bf(v.y) << 16) |
           ((ull)f2bf(v.z) << 32) | ((ull)f2bf(v.w) << 48);
}

__device__ __forceinline__ short8 ld8(const unsigned short* p) {
    return *(const short8*)p;
}

__device__ __forceinline__ ull ald(const ull* p) {
    return __hip_atomic_load(p, __ATOMIC_RELAXED, __HIP_MEMORY_SCOPE_AGENT);
}
__device__ __forceinline__ void ast(ull* p, ull v) {
    __hip_atomic_store(p, v, __ATOMIC_RELAXED, __HIP_MEMORY_SCOPE_AGENT);
}

#define MFMA(A, B, C) __builtin_amdgcn_mfma_f32_16x16x32_bf16((A), (B), (C), 0, 0, 0)

// ---- phase 0: transpose + bf16-convert weights -----------------------------
__global__ void pack_weights(const float* __restrict__ w0, const float* __restrict__ w1,
                             const float* __restrict__ w2, const float* __restrict__ r0,
                             const float* __restrict__ r1, const float* __restrict__ r2,
                             unsigned short* __restrict__ wt, unsigned short* __restrict__ rt) {
    int z = blockIdx.z;
    int K = (z < 3) ? DIN : HD;
    int kb = blockIdx.x * 32;
    if (kb >= K) return;
    int nb = blockIdx.y * 32;
    const float* src = (z == 0) ? w0 : (z == 1) ? w1 : (z == 2) ? w2
                     : (z == 3) ? r0 : (z == 4) ? r1 : r2;
    unsigned short* dst = (z < 3) ? (wt + (size_t)z * HD * DIN)
                                  : (rt + (size_t)(z - 3) * HD * HD);
    __shared__ float tile[32][33];
    int tx = threadIdx.x & 31, ty = threadIdx.x >> 5;
    for (int i = ty; i < 32; i += 8)
        tile[i][tx] = src[(size_t)(kb + i) * HD + nb + tx];
    __syncthreads();
    for (int i = ty; i < 32; i += 8)
        dst[(size_t)(nb + i) * K + kb + tx] = f2bf(tile[tx][i]);
}

// ---- persistent GRU kernel -------------------------------------------------
__launch_bounds__(512, 2)
__global__ void gru_persistent(const float* __restrict__ x,
                               const float* __restrict__ Bz, const float* __restrict__ Br,
                               const float* __restrict__ Bh,
                               const unsigned short* __restrict__ WT,
                               const unsigned short* __restrict__ RT,
                               unsigned short* __restrict__ hbf,
                               unsigned short* __restrict__ rhbf,
                               unsigned* __restrict__ flags,
                               float* __restrict__ out) {
    const int g = blockIdx.x;
    const int group  = g & 7;            // likely XCD id (blockIdx % 8)
    const int member = g >> 3;           // 0..31 within group
    const int rowbase = group * 16;
    const int colbase = member * 32;
    const int tid  = threadIdx.x;
    const int w    = tid >> 6;
    const int lane = tid & 63;
    const int frow = lane & 15;
    const int fquad = lane >> 4;
    const int k0 = fquad * 8;

    // stage A roles
    const int gA = (w >> 2) & 1;         // 0=z, 1=r
    const int cA = (w >> 1) & 1;
    const int hA = w & 1;
    // stage B roles
    const int cB = w & 1;
    const int qB = w >> 1;               // rh K-quarter 0..3
    const int xh = (w >> 1) & 1;         // (w<4) x K-half

    __shared__ unsigned short xsh[16][520];
    __shared__ unsigned short hsh[16][1032];
    __shared__ float zbuf[16][36];
    __shared__ float rtmp[16][36];
    __shared__ float hstate[16][36];
    __shared__ float redA[2][2][4][64];
    __shared__ float redB[2][6][4][64];  // 1..3: rh quarters, 4..5: x halves

    unsigned* gflags = flags + group * 32;   // 128B: 2 cache lines

    if (tid < 128) {
        int row = tid >> 3, c4 = tid & 7;
        *(float4*)&hstate[row][c4 * 4] = make_float4(0.f, 0.f, 0.f, 0.f);
    }

    // ---- weight preload into registers (unified VGPR/AGPR file) -----------
    short8 wAr[24], wBrh[8], wBx[8];
    {
        const unsigned short* wcolA = WT + ((size_t)gA * HD + colbase + cA * 16 + frow) * DIN;
        const unsigned short* rcolA = RT + ((size_t)gA * HD + colbase + cA * 16 + frow) * HD;
        if (hA == 0) {
            #pragma unroll
            for (int i = 0; i < 16; ++i) wAr[i] = ld8(wcolA + i * 32 + k0);
            #pragma unroll
            for (int i = 0; i < 8; ++i)  wAr[16 + i] = ld8(rcolA + i * 32 + k0);
        } else {
            #pragma unroll
            for (int i = 0; i < 24; ++i) wAr[i] = ld8(rcolA + (8 + i) * 32 + k0);
        }
        const unsigned short* rcolB = RT + ((size_t)2 * HD + colbase + cB * 16 + frow) * HD;
        #pragma unroll
        for (int i = 0; i < 8; ++i) wBrh[i] = ld8(rcolB + (qB * 8 + i) * 32 + k0);
        if (w < 4) {
            const unsigned short* wcolB = WT + ((size_t)2 * HD + colbase + cB * 16 + frow) * DIN;
            #pragma unroll
            for (int i = 0; i < 8; ++i) wBx[i] = ld8(wcolB + (xh * 8 + i) * 32 + k0);
        }
    }
    const float bvA = (gA == 0 ? Bz : Br)[colbase + cA * 16 + frow];
    const float bvB = Bh[colbase + cB * 16 + frow];

    const ull* hbf_u = (const ull*)hbf;
    const ull* rh_u  = (const ull*)rhbf;

    // stage x[0]
    for (int i = tid; i < 2048; i += 512) {
        int row = i >> 7, c4 = i & 127;
        *(ull*)&xsh[row][c4 * 4] =
            pack4v(((const float4*)(x + (size_t)(rowbase + row) * TT * DIN))[c4]);
    }
    __syncthreads();

    unsigned phase = 0;

    for (int t = 0; t < TT; ++t) {
        // ---- phase 1: h loads into regs; x@W_h hidden under their latency --
        ull hreg[8];
        {
            const int c8 = tid & 255;
            const int r0r = tid >> 8;
            #pragma unroll
            for (int j = 0; j < 8; ++j)
                hreg[j] = ald(hbf_u + (size_t)(rowbase + r0r + 2 * j) * 256 + c8);
        }
        if (w < 4) {                      // x @ W_h partials (xsh only)
            f32x4 b0 = {0.f,0.f,0.f,0.f}, b1 = {0.f,0.f,0.f,0.f};
            #pragma unroll
            for (int i = 0; i < 8; i += 2) {
                b0 = MFMA(ld8(&xsh[frow][(xh * 8 + i) * 32 + k0]), wBx[i], b0);
                b1 = MFMA(ld8(&xsh[frow][(xh * 8 + i + 1) * 32 + k0]), wBx[i + 1], b1);
            }
            #pragma unroll
            for (int r4 = 0; r4 < 4; ++r4) redB[cB][4 + xh][r4][lane] = b0[r4] + b1[r4];
        }
        {
            const int c8 = tid & 255;
            const int r0r = tid >> 8;
            #pragma unroll
            for (int j = 0; j < 8; ++j)
                *(ull*)&hsh[r0r + 2 * j][c8 * 4] = hreg[j];
        }
        __syncthreads();

        // ---- stage A: z, r ------------------------------------------------
        {
            f32x4 a0 = {0.f,0.f,0.f,0.f}, a1 = {0.f,0.f,0.f,0.f};
            if (hA == 0) {
                #pragma unroll
                for (int i = 0; i < 16; i += 2) {
                    a0 = MFMA(ld8(&xsh[frow][i * 32 + k0]), wAr[i], a0);
                    a1 = MFMA(ld8(&xsh[frow][(i + 1) * 32 + k0]), wAr[i + 1], a1);
                }
                #pragma unroll
                for (int i = 0; i < 8; i += 2) {
                    a0 = MFMA(ld8(&hsh[frow][i * 32 + k0]), wAr[16 + i], a0);
                    a1 = MFMA(ld8(&hsh[frow][(i + 1) * 32 + k0]), wAr[17 + i], a1);
                }
            } else {
                #pragma unroll
                for (int i = 0; i < 24; i += 2) {
                    a0 = MFMA(ld8(&hsh[frow][(8 + i) * 32 + k0]), wAr[i], a0);
                    a1 = MFMA(ld8(&hsh[frow][(9 + i) * 32 + k0]), wAr[i + 1], a1);
                }
                #pragma unroll
                for (int r4 = 0; r4 < 4; ++r4)
                    redA[gA][cA][r4][lane] = a0[r4] + a1[r4];
            }
            __syncthreads();
            if (hA == 0) {
                const int c = cA * 16 + frow;
                #pragma unroll
                for (int r4 = 0; r4 < 4; ++r4) {
                    int row = fquad * 4 + r4;
                    float pre = a0[r4] + a1[r4] + redA[gA][cA][r4][lane] + bvA;
                    float sg = 1.f / (1.f + __expf(-pre));
                    if (gA == 0) zbuf[row][c] = sg;
                    else         rtmp[row][c] = sg * hstate[row][c];
                }
            }
        }
        __syncthreads();
        if (tid < 128) {                               // publish r*h
            int row = tid >> 3, c4 = tid & 7;
            ast((ull*)rhbf + (size_t)(rowbase + row) * 256 + (colbase >> 2) + c4,
                pack4(&rtmp[row][c4 * 4]));
        }
        __syncthreads();                               // drain publishes
        ++phase;
        if (tid == 0)
            __hip_atomic_store(gflags + member, phase,
                               __ATOMIC_RELAXED, __HIP_MEMORY_SCOPE_AGENT);
        if (t + 1 < TT) {                              // x[t+1]: overlaps poll
            for (int i = tid; i < 2048; i += 512) {
                int row = i >> 7, c4 = i & 127;
                *(ull*)&xsh[row][c4 * 4] =
                    pack4v(((const float4*)(x + ((size_t)(rowbase + row) * TT + t + 1) * DIN))[c4]);
            }
        }
        if (tid < 32) {
            while (__hip_atomic_load(gflags + tid, __ATOMIC_RELAXED,
                                     __HIP_MEMORY_SCOPE_AGENT) < phase)
                __builtin_amdgcn_s_sleep(1);
        }
        __syncthreads();

        // ---- phase 2: (r*h)@R_h, A-fragments direct from L3 ---------------
        {
            f32x4 b0 = {0.f,0.f,0.f,0.f}, b1 = {0.f,0.f,0.f,0.f};
            const ull* rrow = rh_u + (size_t)(rowbase + frow) * 256 + qB * 64 + fquad * 2;
            union { ull u[2]; short8 s; } fr[8];
            #pragma unroll
            for (int i = 0; i < 8; ++i) {
                fr[i].u[0] = ald(rrow + i * 8);
                fr[i].u[1] = ald(rrow + i * 8 + 1);
            }
            #pragma unroll
            for (int i = 0; i < 8; i += 2) {
                b0 = MFMA(fr[i].s, wBrh[i], b0);
                b1 = MFMA(fr[i + 1].s, wBrh[i + 1], b1);
            }
            if (qB > 0) {
                #pragma unroll
                for (int r4 = 0; r4 < 4; ++r4)
                    redB[cB][qB][r4][lane] = b0[r4] + b1[r4];
            }
            __syncthreads();
            if (qB == 0) {
                const int c = cB * 16 + frow;
                #pragma unroll
                for (int r4 = 0; r4 < 4; ++r4) {
                    int row = fquad * 4 + r4;
                    float pre = b0[r4] + b1[r4]
                              + redB[cB][1][r4][lane] + redB[cB][2][r4][lane]
                              + redB[cB][3][r4][lane]
                              + redB[cB][4][r4][lane] + redB[cB][5][r4][lane] + bvB;
                    float e = __expf(2.f * pre);       // tanh = 1 - 2/(e+1)
                    float ht = 1.f - 2.f / (e + 1.f);
                    float zv = zbuf[row][c];
                    float ho = hstate[row][c];
                    hstate[row][c] = ho + zv * (ht - ho);
                }
            }
        }
        __syncthreads();

        if (t + 1 < TT) {
            if (tid < 128) {                           // publish h
                int row = tid >> 3, c4 = tid & 7;
                ast((ull*)hbf + (size_t)(rowbase + row) * 256 + (colbase >> 2) + c4,
                    pack4(&hstate[row][c4 * 4]));
            }
            __syncthreads();                           // drain publishes
            ++phase;
            if (tid == 0)
                __hip_atomic_store(gflags + member, phase,
                                   __ATOMIC_RELAXED, __HIP_MEMORY_SCOPE_AGENT);
            if (tid < 32) {
                while (__hip_atomic_load(gflags + tid, __ATOMIC_RELAXED,
                                         __HIP_MEMORY_SCOPE_AGENT) < phase)
                    __builtin_amdgcn_s_sleep(1);
            }
            __syncthreads();
        }
    }

    if (tid < 128) {                                   // final output, fp32
        int row = tid >> 3, c4 = tid & 7;
        *(float4*)(out + (size_t)(rowbase + row) * HD + colbase + c4 * 4) =
            *(float4*)&hstate[row][c4 * 4];
    }
}

extern "C" void kernel_launch(void* const* d_in, const int* in_sizes, int n_in,
                              void* d_out, int out_size, void* d_ws, size_t ws_size,
                              hipStream_t stream) {
    const float* x  = (const float*)d_in[0];
    const float* Wz = (const float*)d_in[1];
    const float* Wr = (const float*)d_in[2];
    const float* Wh = (const float*)d_in[3];
    const float* Rz = (const float*)d_in[4];
    const float* Rr = (const float*)d_in[5];
    const float* Rh = (const float*)d_in[6];
    const float* Bz = (const float*)d_in[7];
    const float* Br = (const float*)d_in[8];
    const float* Bh = (const float*)d_in[9];

    char* ws = (char*)d_ws;
    unsigned*       flags = (unsigned*)(ws + FLAGS_OFF);
    unsigned short* WT    = (unsigned short*)(ws + WT_OFF);
    unsigned short* RT    = (unsigned short*)(ws + RT_OFF);
    unsigned short* hbf   = (unsigned short*)(ws + HBF_OFF);
    unsigned short* rhbf  = (unsigned short*)(ws + RH_OFF);

    hipMemsetAsync(ws + FLAGS_OFF, 0, 1024, stream);         // flags = 0
    hipMemsetAsync(ws + HBF_OFF, 0, BB * HD * 2, stream);    // h0 = 0

    dim3 pgrid(HD / 32, HD / 32, 6);
    pack_weights<<<pgrid, 256, 0, stream>>>(Wz, Wr, Wh, Rz, Rr, Rh, WT, RT);

    gru_persistent<<<256, 512, 0, stream>>>(x, Bz, Br, Bh, WT, RT, hbf, rhbf,
                                            flags, (float*)d_out);
}